// Round 2
// baseline (8791.782 us; speedup 1.0000x reference)
//
#include <hip/hip_runtime.h>

// DA-RNN fused kernel: one block per batch element, encoder + decoder + head.
// B=1024, T=100, M=H=P=128, C=32. All global I/O fp32; LDS slabs bf16.
//
// R2: spill fix — amdgpu_waves_per_eu(2) lifts the VGPR cap 128->256 so the
// per-thread weight arrays (192 regs) stay register-resident (R1: 281 MB of
// scratch WRITE_SIZE). 4-way accumulator ILP in both 128-wide matvecs.

typedef unsigned int  u32;
typedef unsigned short u16;

#define T_ 100
#define C_ 32

__device__ __forceinline__ float bf2f(u16 u) {
  union { u32 i; float f; } v; v.i = ((u32)u) << 16; return v.f;
}
__device__ __forceinline__ u16 f2bf(float f) {
  union { float f; u32 i; } v; v.f = f;
  u32 r = v.i + 0x7fffu + ((v.i >> 16) & 1u);   // round-to-nearest-even
  return (u16)(r >> 16);
}
__device__ __forceinline__ void unpk(u32 p, float& lo, float& hi) {
  union { u32 i; float f; } a, b;
  a.i = p << 16; b.i = p & 0xffff0000u;
  lo = a.f; hi = b.f;
}
__device__ __forceinline__ u32 pk2(float a, float b) {
  return ((u32)f2bf(b) << 16) | (u32)f2bf(a);
}

#if __has_builtin(__builtin_amdgcn_rcpf)
__device__ __forceinline__ float rcpf_(float x){ return __builtin_amdgcn_rcpf(x); }
#else
__device__ __forceinline__ float rcpf_(float x){ return 1.0f / x; }
#endif
__device__ __forceinline__ float sigm(float x){ return rcpf_(1.0f + __expf(-x)); }
__device__ __forceinline__ float tanh_(float x){
  // 1 - 2/(1+e^{2x}); exact at +-inf, ~1e-7 abs error in the tiny-signal regime here
  return 1.0f - 2.0f * rcpf_(1.0f + __expf(2.0f * x));
}

__device__ __forceinline__ float wsum(float v){
  #pragma unroll
  for (int o = 32; o; o >>= 1) v += __shfl_xor(v, o, 64);
  return v;
}
__device__ __forceinline__ float wmax(float v){
  #pragma unroll
  for (int o = 32; o; o >>= 1) v = fmaxf(v, __shfl_xor(v, o, 64));
  return v;
}

__global__ void
__attribute__((amdgpu_flat_work_group_size(512, 512)))
__attribute__((amdgpu_waves_per_eu(2)))
darnn_fused(const float* __restrict__ X,
            const float* __restrict__ eWih, const float* __restrict__ eWhh,
            const float* __restrict__ ebih, const float* __restrict__ ebhh,
            const float* __restrict__ eAw,  const float* __restrict__ eAb,
            const float* __restrict__ dW1,  const float* __restrict__ db1,
            const float* __restrict__ dW2,  const float* __restrict__ db2,
            const float* __restrict__ dWih, const float* __restrict__ dWhh,
            const float* __restrict__ dbih, const float* __restrict__ dbhh,
            const float* __restrict__ fcW,  const float* __restrict__ fcb,
            const float* __restrict__ fcfW, const float* __restrict__ fcfb,
            float* __restrict__ out)
{
  // LDS: 25600+25600+2048+512*5+64 = ~58.1 KB (< 64 KB/WG)
  __shared__ __align__(16) u16   sxh[12800];   // phase-enc: x_tilde bf16; phase-dec: E1 bf16
  __shared__ __align__(16) u16   sxe[12800];   // X_enc bf16
  __shared__ __align__(16) float sg[512];      // gates
  __shared__ __align__(16) float sh[128];      // h (enc) / d (dec)
  __shared__ __align__(16) float sc[128];      // c
  __shared__ __align__(16) float su[128];      // alpha (prologue) / u (dec)
  __shared__ __align__(16) float spart[512];   // u partials / ctx partials
  __shared__ __align__(16) float sscore[128];  // scores -> beta
  __shared__ __align__(16) float sctx[128];    // ctx
  __shared__ float sred[8];

  const int tid  = threadIdx.x;
  const int lane = tid & 63;
  const int wv   = tid >> 6;
  const int b    = blockIdx.x;
  const int hh   = tid & 127;  // split-role h index
  const int qq   = tid >> 7;   // 0..3

  // ================= encoder prologue =================
  {
    const float* Xb = X + (size_t)b * (T_ * 128);
    #pragma unroll
    for (int r = 0; r < 25; ++r) {
      int idx = tid + 512 * r;
      sxh[idx] = f2bf(Xb[idx]);
    }
  }
  __syncthreads();

  // alpha[m] = softmax_m( sum_t X[b,t,m] * eAw[256+t] )  (h/c terms cancel)
  float sval = 0.f;
  if (tid < 128) {
    #pragma unroll 4
    for (int t = 0; t < T_; ++t)
      sval += bf2f(sxh[t * 128 + tid]) * eAw[256 + t];
  }
  float mx = wmax(sval);
  if (lane == 0 && wv < 2) sred[wv] = mx;
  __syncthreads();
  float gmax = fmaxf(sred[0], sred[1]);
  float ee = (tid < 128) ? __expf(sval - gmax) : 0.f;
  float sm = wsum(ee);
  if (lane == 0 && wv < 2) sred[2 + wv] = sm;
  __syncthreads();
  if (tid < 128) {
    su[tid] = ee * rcpf_(sred[2] + sred[3]);
    sh[tid] = 0.f;
    sc[tid] = 0.f;
  }
  __syncthreads();
  // fold alpha into X  ->  x_tilde
  #pragma unroll
  for (int r = 0; r < 25; ++r) {
    int idx = tid + 512 * r;
    sxh[idx] = f2bf(bf2f(sxh[idx]) * su[idx & 127]);
  }

  // encoder weights -> registers: Whh row (fp32), Wih row (bf16 pairs)
  float wa[128];
  u32   wpk[64];
  {
    const float4* wr = (const float4*)(eWhh + (size_t)tid * 128);
    #pragma unroll
    for (int i = 0; i < 32; ++i) {
      float4 v = wr[i];
      wa[4*i+0] = v.x; wa[4*i+1] = v.y; wa[4*i+2] = v.z; wa[4*i+3] = v.w;
    }
    const float4* wi = (const float4*)(eWih + (size_t)tid * 128);
    #pragma unroll
    for (int i = 0; i < 32; ++i) {
      float4 v = wi[i];
      wpk[2*i+0] = pk2(v.x, v.y);
      wpk[2*i+1] = pk2(v.z, v.w);
    }
  }
  float biasg = ebih[tid] + ebhh[tid];
  (void)eAb; // cancels in softmax
  __syncthreads();

  // ================= encoder recurrence =================
  for (int t = 0; t < T_; ++t) {
    float g0 = biasg, g1 = 0.f, g2 = 0.f, g3 = 0.f;
    {
      const float4* h4 = (const float4*)sh;
      #pragma unroll
      for (int k = 0; k < 32; ++k) {
        float4 hv = h4[k];
        g0 += wa[4*k+0]*hv.x; g1 += wa[4*k+1]*hv.y;
        g2 += wa[4*k+2]*hv.z; g3 += wa[4*k+3]*hv.w;
      }
    }
    {
      const uint4* xr = (const uint4*)(sxh + t * 128);
      #pragma unroll
      for (int k = 0; k < 16; ++k) {
        uint4 xp = xr[k];
        float xl, xh, wl, wh;
        unpk(xp.x, xl, xh); unpk(wpk[4*k+0], wl, wh); g0 += wl*xl; g1 += wh*xh;
        unpk(xp.y, xl, xh); unpk(wpk[4*k+1], wl, wh); g2 += wl*xl; g3 += wh*xh;
        unpk(xp.z, xl, xh); unpk(wpk[4*k+2], wl, wh); g0 += wl*xl; g1 += wh*xh;
        unpk(xp.w, xl, xh); unpk(wpk[4*k+3], wl, wh); g2 += wl*xl; g3 += wh*xh;
      }
    }
    sg[tid] = (g0 + g1) + (g2 + g3);
    __syncthreads();
    if (tid < 128) {
      float gi = sigm(sg[tid]);
      float gf = sigm(sg[tid + 128]);
      float gg = tanh_(sg[tid + 256]);
      float go = sigm(sg[tid + 384]);
      float c  = gf * sc[tid] + gi * gg;
      sc[tid]  = c;
      float h  = go * tanh_(c);
      sh[tid]  = h;
      sxe[t * 128 + tid] = f2bf(h);
    }
    __syncthreads();
  }

  // ================= decoder prologue =================
  // E1[t][h] = sum_k Xe[t][k] * dW1[h][256+k] + db1[h]  -> sxh (reuse)
  {
    float acc[25];
    #pragma unroll
    for (int i = 0; i < 25; ++i) acc[i] = 0.f;
    const float* w1x = dW1 + (size_t)hh * 384 + 256;
    for (int kb = 0; kb < 4; ++kb) {
      float wt[32];
      {
        const float4* w4 = (const float4*)(w1x + kb * 32);
        #pragma unroll
        for (int i = 0; i < 8; ++i) {
          float4 v = w4[i];
          wt[4*i+0] = v.x; wt[4*i+1] = v.y; wt[4*i+2] = v.z; wt[4*i+3] = v.w;
        }
      }
      #pragma unroll
      for (int i = 0; i < 25; ++i) {
        const uint4* xr = (const uint4*)(sxe + (qq * 25 + i) * 128 + kb * 32);
        float a0 = 0.f, a1 = 0.f, a2 = 0.f, a3 = 0.f;
        #pragma unroll
        for (int k4 = 0; k4 < 4; ++k4) {
          uint4 xp = xr[k4];
          float l0,h0,l1,h1,l2,h2,l3,h3;
          unpk(xp.x, l0, h0); unpk(xp.y, l1, h1);
          unpk(xp.z, l2, h2); unpk(xp.w, l3, h3);
          a0 += wt[8*k4+0]*l0 + wt[8*k4+1]*h0;
          a1 += wt[8*k4+2]*l1 + wt[8*k4+3]*h1;
          a2 += wt[8*k4+4]*l2 + wt[8*k4+5]*h2;
          a3 += wt[8*k4+6]*l3 + wt[8*k4+7]*h3;
        }
        acc[i] += (a0 + a1) + (a2 + a3);
      }
    }
    float b1v = db1[hh];
    #pragma unroll
    for (int i = 0; i < 25; ++i)
      sxh[(qq * 25 + i) * 128 + hh] = f2bf(acc[i] + b1v);
  }

  // decoder weights -> same register arrays (forces reuse):
  // wa = dWhh row j (fp32); wpk[0:16] = W1d quarter-row, wpk[16:32] = W1c quarter-row (bf16 pairs)
  {
    const float4* wr = (const float4*)(dWhh + (size_t)tid * 128);
    #pragma unroll
    for (int i = 0; i < 32; ++i) {
      float4 v = wr[i];
      wa[4*i+0] = v.x; wa[4*i+1] = v.y; wa[4*i+2] = v.z; wa[4*i+3] = v.w;
    }
    const float* w1d = dW1 + (size_t)hh * 384 + qq * 32;
    const float* w1c = w1d + 128;
    #pragma unroll
    for (int i = 0; i < 16; ++i) wpk[i]      = pk2(w1d[2*i], w1d[2*i+1]);
    #pragma unroll
    for (int i = 0; i < 16; ++i) wpk[16 + i] = pk2(w1c[2*i], w1c[2*i+1]);
  }
  float biasD = dbih[tid] + dbhh[tid];
  float wihj  = dWih[tid];
  float w2a   = dW2[lane];
  float w2b   = dW2[lane + 64];
  float b2v   = db2[0];
  float fcbv  = fcb[0];
  float fcwv  = (tid < 128) ? fcW[tid] : 0.f;
  if (tid < 128) { sh[tid] = 0.f; sc[tid] = 0.f; }  // d0, c0
  __syncthreads();

  // ================= decoder recurrence =================
  for (int step = 0; step < T_; ++step) {
    // S0: u partials: u[h] = sum_p W1d[h,p]*d[p] + W1c[h,p]*c[p]  (split-K over qq)
    {
      float pu0 = 0.f, pu1 = 0.f;
      const float2* d2 = ((const float2*)sh) + 16 * qq;
      const float2* c2 = ((const float2*)sc) + 16 * qq;
      #pragma unroll
      for (int i = 0; i < 16; ++i) {
        float wl, wh;
        float2 dv = d2[i];
        unpk(wpk[i], wl, wh);      pu0 += wl * dv.x + wh * dv.y;
        float2 cv = c2[i];
        unpk(wpk[16 + i], wl, wh); pu1 += wl * cv.x + wh * cv.y;
      }
      spart[tid] = pu0 + pu1;
    }
    __syncthreads();
    // S1: reduce u
    if (tid < 128)
      su[tid] = spart[tid] + spart[tid + 128] + spart[tid + 256] + spart[tid + 384];
    __syncthreads();
    // S2: scores: score[t] = sum_h w2[h]*tanh(E1[t,h]+u[h]) + b2
    {
      float ul = su[lane], uh = su[lane + 64];
      for (int t = wv; t < T_; t += 8) {
        float v = w2a * tanh_(bf2f(sxh[t * 128 + lane]) + ul)
                + w2b * tanh_(bf2f(sxh[t * 128 + 64 + lane]) + uh);
        v = wsum(v);
        if (lane == 0) sscore[t] = v + b2v;
      }
    }
    __syncthreads();
    // S3: softmax over t (wave 0)
    if (wv == 0) {
      float s0 = sscore[lane];
      float s1 = (lane < 36) ? sscore[lane + 64] : -3.0e38f;
      float m  = wmax(fmaxf(s0, s1));
      float e0 = __expf(s0 - m);
      float e1 = (lane < 36) ? __expf(s1 - m) : 0.f;
      float s  = wsum(e0 + e1);
      float iv = rcpf_(s);
      sscore[lane] = e0 * iv;
      if (lane < 36) sscore[lane + 64] = e1 * iv;
    }
    __syncthreads();
    // S4: ctx partials: ctx[h] = sum_t beta[t]*Xe[t,h]  (split over qq's t-range)
    {
      float pc0 = 0.f, pc1 = 0.f;
      #pragma unroll
      for (int i = 0; i < 25; i += 2) {
        int t = qq * 25 + i;
        pc0 += sscore[t] * bf2f(sxe[t * 128 + hh]);
        if (i + 1 < 25) {
          int t1 = t + 1;
          pc1 += sscore[t1] * bf2f(sxe[t1 * 128 + hh]);
        }
      }
      spart[tid] = pc0 + pc1;
    }
    __syncthreads();
    // S5: ctx final + y_tilde partial
    {
      float v = 0.f;
      if (tid < 128) {
        float cx = spart[tid] + spart[tid + 128] + spart[tid + 256] + spart[tid + 384];
        sctx[tid] = cx;
        v = fcwv * cx;
      }
      v = wsum(v);
      if (lane == 0 && wv < 2) sred[wv] = v;
    }
    __syncthreads();
    // S6: gates: g[j] = biasD + Wih[j]*y + sum_k Whh[j,k]*d[k]
    {
      float yt = sred[0] + sred[1] + fcbv;
      float g0 = biasD + wihj * yt, g1 = 0.f, g2 = 0.f, g3 = 0.f;
      const float4* h4 = (const float4*)sh;
      #pragma unroll
      for (int k = 0; k < 32; ++k) {
        float4 hv = h4[k];
        g0 += wa[4*k+0]*hv.x; g1 += wa[4*k+1]*hv.y;
        g2 += wa[4*k+2]*hv.z; g3 += wa[4*k+3]*hv.w;
      }
      sg[tid] = (g0 + g1) + (g2 + g3);
    }
    __syncthreads();
    // S7: pointwise LSTM
    if (tid < 128) {
      float gi = sigm(sg[tid]);
      float gf = sigm(sg[tid + 128]);
      float gg = tanh_(sg[tid + 256]);
      float go = sigm(sg[tid + 384]);
      float c  = gf * sc[tid] + gi * gg;
      sc[tid]  = c;
      sh[tid]  = go * tanh_(c);
    }
    __syncthreads();
  }

  // ================= head: out = [d, ctx] @ fcfW^T + fcfb =================
  if (tid < C_) {
    float acc = fcfb[tid];
    const float* w = fcfW + (size_t)tid * 256;
    #pragma unroll 8
    for (int k = 0; k < 128; ++k)
      acc += w[k] * sh[k] + w[128 + k] * sctx[k];
    out[(size_t)b * C_ + tid] = acc;
  }
}

extern "C" void kernel_launch(void* const* d_in, const int* in_sizes, int n_in,
                              void* d_out, int out_size, void* d_ws, size_t ws_size,
                              hipStream_t stream) {
  (void)n_in; (void)out_size; (void)d_ws; (void)ws_size;
  const float* X    = (const float*)d_in[0];
  const float* eWih = (const float*)d_in[1];
  const float* eWhh = (const float*)d_in[2];
  const float* ebih = (const float*)d_in[3];
  const float* ebhh = (const float*)d_in[4];
  const float* eAw  = (const float*)d_in[5];
  const float* eAb  = (const float*)d_in[6];
  const float* dW1  = (const float*)d_in[7];
  const float* db1  = (const float*)d_in[8];
  const float* dW2  = (const float*)d_in[9];
  const float* db2  = (const float*)d_in[10];
  const float* dWih = (const float*)d_in[11];
  const float* dWhh = (const float*)d_in[12];
  const float* dbih = (const float*)d_in[13];
  const float* dbhh = (const float*)d_in[14];
  const float* fcW  = (const float*)d_in[15];
  const float* fcb  = (const float*)d_in[16];
  const float* fcfW = (const float*)d_in[17];
  const float* fcfb = (const float*)d_in[18];
  float* out = (float*)d_out;

  const int B = in_sizes[0] / (T_ * 128);
  darnn_fused<<<dim3(B), dim3(512), 0, stream>>>(
      X, eWih, eWhh, ebih, ebhh, eAw, eAb,
      dW1, db1, dW2, db2, dWih, dWhh, dbih, dbhh,
      fcW, fcb, fcfW, fcfb, out);
}

// Round 3
// 2633.708 us; speedup vs baseline: 3.3382x; 3.3382x over previous
//
#include <hip/hip_runtime.h>

// DA-RNN fused kernel: one block per batch element, encoder + decoder + head.
// B=1024, T=100, M=H=P=128, C=32. Global I/O fp32; LDS slabs + weights bf16.
//
// R3: spill-proof restructure. 1024 threads (16 waves, natural VGPR budget
// 128). Each gate row j=tid>>1 is split across a thread PAIR (half=tid&1 owns
// 64 of 128 K-elements); ALL persistent weights bf16-packed => per-phase
// register arrays 48..77 u32, peak ~95 VGPR < 128 (R1/R2 spilled at ~220).
// Matvecs use v_dot2_f32_bf16 (2 MAC/instr, full VALU rate). Pair-combine via
// __shfl_xor(g,1).

typedef unsigned int   u32;
typedef unsigned short u16;

#define T_ 100
#define C_ 32
#define NT 1024

__device__ __forceinline__ float bf2f(u16 u) {
  union { u32 i; float f; } v; v.i = ((u32)u) << 16; return v.f;
}
__device__ __forceinline__ u16 f2bf(float f) {
  union { float f; u32 i; } v; v.f = f;
  u32 r = v.i + 0x7fffu + ((v.i >> 16) & 1u);   // round-to-nearest-even
  return (u16)(r >> 16);
}
__device__ __forceinline__ void unpk(u32 p, float& lo, float& hi) {
  union { u32 i; float f; } a, b;
  a.i = p << 16; b.i = p & 0xffff0000u;
  lo = a.f; hi = b.f;
}
__device__ __forceinline__ u32 pk2(float a, float b) {
  return ((u32)f2bf(b) << 16) | (u32)f2bf(a);
}

typedef __attribute__((ext_vector_type(2))) __bf16 bf16x2;

#if __has_builtin(__builtin_amdgcn_fdot2_f32_bf16)
#define HAVE_DOT2 1
#else
#define HAVE_DOT2 0
#endif

// acc += dot2(bf16pair w, bf16pair x) — v_dot2_f32_bf16: 2 MAC per VALU instr
__device__ __forceinline__ float dot2bf(u32 w, u32 x, float acc) {
#if HAVE_DOT2
  return __builtin_amdgcn_fdot2_f32_bf16(__builtin_bit_cast(bf16x2, w),
                                         __builtin_bit_cast(bf16x2, x),
                                         acc, false);
#else
  float a, b, c, d;
  unpk(w, a, b); unpk(x, c, d);
  return acc + a * c + b * d;
#endif
}

#if __has_builtin(__builtin_amdgcn_rcpf)
__device__ __forceinline__ float rcpf_(float x){ return __builtin_amdgcn_rcpf(x); }
#else
__device__ __forceinline__ float rcpf_(float x){ return 1.0f / x; }
#endif
__device__ __forceinline__ float sigm(float x){ return rcpf_(1.0f + __expf(-x)); }
__device__ __forceinline__ float tanh_(float x){
  return 1.0f - 2.0f * rcpf_(1.0f + __expf(2.0f * x));
}

__device__ __forceinline__ float wsum(float v){
  #pragma unroll
  for (int o = 32; o; o >>= 1) v += __shfl_xor(v, o, 64);
  return v;
}
__device__ __forceinline__ float wmax(float v){
  #pragma unroll
  for (int o = 32; o; o >>= 1) v = fmaxf(v, __shfl_xor(v, o, 64));
  return v;
}

__global__ void __launch_bounds__(NT)
darnn_fused(const float* __restrict__ X,
            const float* __restrict__ eWih, const float* __restrict__ eWhh,
            const float* __restrict__ ebih, const float* __restrict__ ebhh,
            const float* __restrict__ eAw,  const float* __restrict__ eAb,
            const float* __restrict__ dW1,  const float* __restrict__ db1,
            const float* __restrict__ dW2,  const float* __restrict__ db2,
            const float* __restrict__ dWih, const float* __restrict__ dWhh,
            const float* __restrict__ dbih, const float* __restrict__ dbhh,
            const float* __restrict__ fcW,  const float* __restrict__ fcb,
            const float* __restrict__ fcfW, const float* __restrict__ fcfb,
            float* __restrict__ out)
{
  // LDS total ~60.4 KB < 64 KB
  __shared__ __align__(16) u16   sxh[12800];   // enc: x_tilde bf16; dec: E1 bf16
  __shared__ __align__(16) u16   sxe[12800];   // X_enc bf16
  __shared__ __align__(16) float sg[512];      // gates
  __shared__ __align__(16) float sh[128];      // h (enc) / d (dec), fp32
  __shared__ __align__(16) float sc[128];      // c, fp32
  __shared__ __align__(16) u16   shp[128];     // h/d packed bf16
  __shared__ __align__(16) u16   scp[128];     // c packed bf16
  __shared__ __align__(16) float su[128];      // alpha (prologue) / u (dec)
  __shared__ __align__(16) float spart[NT];    // partials
  __shared__ __align__(16) float sscore[128];  // scores -> beta
  __shared__ __align__(16) float sctx[128];    // ctx
  __shared__ float sred[8];

  const int tid  = threadIdx.x;
  const int lane = tid & 63;
  const int wv   = tid >> 6;   // 0..15
  const int b    = blockIdx.x;
  const int r    = tid >> 1;   // gate row 0..511
  const int hf   = tid & 1;    // K-half
  const int hh   = tid & 127;  // h index for split-role stages
  const int oct  = tid >> 7;   // 0..7

  // ================= encoder prologue =================
  {
    const float4* Xb4 = (const float4*)(X + (size_t)b * 12800);
    u32* dst = (u32*)sxh;
    #pragma unroll
    for (int i = 0; i < 4; ++i) {
      int idx = tid + NT * i;          // float4 index, < 3200
      if (idx < 3200) {
        float4 v = Xb4[idx];
        dst[2 * idx]     = pk2(v.x, v.y);
        dst[2 * idx + 1] = pk2(v.z, v.w);
      }
    }
  }
  __syncthreads();

  // alpha[m] = softmax_m( sum_t X[b,t,m] * eAw[256+t] )  (h/c terms cancel)
  float sval = 0.f;
  if (tid < 128) {
    #pragma unroll 4
    for (int t = 0; t < T_; ++t)
      sval += bf2f(sxh[t * 128 + tid]) * eAw[256 + t];
  }
  float mx = wmax(sval);
  if (lane == 0 && wv < 2) sred[wv] = mx;
  __syncthreads();
  float gmax = fmaxf(sred[0], sred[1]);
  float ee = (tid < 128) ? __expf(sval - gmax) : 0.f;
  float sm = wsum(ee);
  if (lane == 0 && wv < 2) sred[2 + wv] = sm;
  __syncthreads();
  if (tid < 128) {
    su[tid] = ee * rcpf_(sred[2] + sred[3]);
    sh[tid] = 0.f; sc[tid] = 0.f;
    shp[tid] = 0;  scp[tid] = 0;
  }
  __syncthreads();
  // fold alpha into X  ->  x_tilde  (process as u32 pairs)
  {
    u32* sx32 = (u32*)sxh;
    #pragma unroll
    for (int i = 0; i < 7; ++i) {
      int p = tid + NT * i;
      if (p < 6400) {
        float lo, hi; unpk(sx32[p], lo, hi);
        int m = (2 * p) & 127;
        sx32[p] = pk2(lo * su[m], hi * su[m + 1]);
      }
    }
  }

  // encoder weights -> registers, bf16 packed. Thread owns row r, half hf:
  // elements [hf*64, hf*64+64). Global addr = row*128 + hf*64 = tid*64.
  u32 wpkH[32], wpkI[32];
  {
    const float4* wr = (const float4*)(eWhh + (size_t)tid * 64);
    #pragma unroll
    for (int i = 0; i < 16; ++i) {
      float4 v = wr[i];
      wpkH[2 * i]     = pk2(v.x, v.y);
      wpkH[2 * i + 1] = pk2(v.z, v.w);
    }
    const float4* wi = (const float4*)(eWih + (size_t)tid * 64);
    #pragma unroll
    for (int i = 0; i < 16; ++i) {
      float4 v = wi[i];
      wpkI[2 * i]     = pk2(v.x, v.y);
      wpkI[2 * i + 1] = pk2(v.z, v.w);
    }
  }
  float biasg = (hf == 0) ? (ebih[r] + ebhh[r]) : 0.f;
  (void)eAb; // cancels in softmax
  __syncthreads();

  // ================= encoder recurrence =================
  for (int t = 0; t < T_; ++t) {
    const uint4* xr4 = (const uint4*)((const u32*)(sxh + t * 128) + hf * 32);
    const uint4* hr4 = (const uint4*)((const u32*)shp + hf * 32);
    float a0 = 0.f, a1 = 0.f, a2 = 0.f, a3 = 0.f;
    #pragma unroll
    for (int i = 0; i < 8; ++i) {
      uint4 hv = hr4[i];
      uint4 xv = xr4[i];
      a0 = dot2bf(wpkH[4*i+0], hv.x, a0);
      a1 = dot2bf(wpkH[4*i+1], hv.y, a1);
      a0 = dot2bf(wpkH[4*i+2], hv.z, a0);
      a1 = dot2bf(wpkH[4*i+3], hv.w, a1);
      a2 = dot2bf(wpkI[4*i+0], xv.x, a2);
      a3 = dot2bf(wpkI[4*i+1], xv.y, a3);
      a2 = dot2bf(wpkI[4*i+2], xv.z, a2);
      a3 = dot2bf(wpkI[4*i+3], xv.w, a3);
    }
    float g = biasg + (a0 + a1) + (a2 + a3);
    g += __shfl_xor(g, 1, 64);           // combine the two K-halves
    if (hf == 0) sg[r] = g;
    __syncthreads();
    if (tid < 128) {
      float gi = sigm(sg[tid]);
      float gf = sigm(sg[tid + 128]);
      float gg = tanh_(sg[tid + 256]);
      float go = sigm(sg[tid + 384]);
      float c  = gf * sc[tid] + gi * gg;
      sc[tid]  = c;
      float h  = go * tanh_(c);
      sh[tid]  = h;
      u16 hb   = f2bf(h);
      shp[tid] = hb;
      scp[tid] = f2bf(c);
      sxe[t * 128 + tid] = hb;
    }
    __syncthreads();
  }

  // ================= decoder prologue =================
  // E1[t][h] = sum_k Xe[t][k] * dW1[h][256+k] + db1[h]  -> sxh (reuse)
  // thread: h = hh, t = oct + 8*i
  {
    u32 wtp[64];
    const float4* w4 = (const float4*)(dW1 + (size_t)hh * 384 + 256);
    #pragma unroll
    for (int i = 0; i < 32; ++i) {
      float4 v = w4[i];
      wtp[2 * i]     = pk2(v.x, v.y);
      wtp[2 * i + 1] = pk2(v.z, v.w);
    }
    float b1v = db1[hh];
    for (int i = 0; i < 13; ++i) {
      int t = oct + 8 * i;
      if (t < T_) {
        const uint4* xe4 = (const uint4*)(sxe + t * 128);
        float a0 = 0.f, a1 = 0.f;
        #pragma unroll
        for (int k = 0; k < 8; ++k) {
          uint4 xv = xe4[k];
          a0 = dot2bf(wtp[4*k+0], xv.x, a0);
          a1 = dot2bf(wtp[4*k+1], xv.y, a1);
          a0 = dot2bf(wtp[4*k+2], xv.z, a0);
          a1 = dot2bf(wtp[4*k+3], xv.w, a1);
        }
        const uint4* xe4b = xe4 + 8;
        #pragma unroll
        for (int k = 0; k < 8; ++k) {
          uint4 xv = xe4b[k];
          a0 = dot2bf(wtp[32 + 4*k+0], xv.x, a0);
          a1 = dot2bf(wtp[32 + 4*k+1], xv.y, a1);
          a0 = dot2bf(wtp[32 + 4*k+2], xv.z, a0);
          a1 = dot2bf(wtp[32 + 4*k+3], xv.w, a1);
        }
        sxh[t * 128 + hh] = f2bf(a0 + a1 + b1v);
      }
    }
  }

  // decoder weights -> registers (bf16 packed)
  u32 wpkD[32];   // dWhh row r, half hf
  {
    const float4* wr = (const float4*)(dWhh + (size_t)tid * 64);
    #pragma unroll
    for (int i = 0; i < 16; ++i) {
      float4 v = wr[i];
      wpkD[2 * i]     = pk2(v.x, v.y);
      wpkD[2 * i + 1] = pk2(v.z, v.w);
    }
  }
  u32 wtpU[16];   // u-dot: W1d[h, oct*16..+16), W1c same range
  {
    const float* w1d = dW1 + (size_t)hh * 384 + oct * 16;
    const float* w1c = w1d + 128;
    #pragma unroll
    for (int i = 0; i < 8; ++i) wtpU[i]     = pk2(w1d[2*i], w1d[2*i+1]);
    #pragma unroll
    for (int i = 0; i < 8; ++i) wtpU[8 + i] = pk2(w1c[2*i], w1c[2*i+1]);
  }
  float biasD = (hf == 0) ? (dbih[r] + dbhh[r]) : 0.f;
  float wihj  = (hf == 0) ? dWih[r] : 0.f;
  float w2a   = dW2[lane];
  float w2b   = dW2[lane + 64];
  float b2v   = db2[0];
  float fcbv  = fcb[0];
  float fcwv  = (tid < 128) ? fcW[tid] : 0.f;
  if (tid < 128) { sh[tid] = 0.f; sc[tid] = 0.f; shp[tid] = 0; scp[tid] = 0; }
  __syncthreads();

  // ================= decoder recurrence =================
  for (int step = 0; step < T_; ++step) {
    // S0: u partials: u[h] = sum_p W1d[h,p]*d[p] + W1c[h,p]*c[p]
    {
      const uint4* dp = (const uint4*)((const u32*)shp + oct * 8);
      const uint4* cp = (const uint4*)((const u32*)scp + oct * 8);
      uint4 d0 = dp[0], d1 = dp[1];
      uint4 c0 = cp[0], c1 = cp[1];
      float a0 = 0.f, a1 = 0.f;
      a0 = dot2bf(wtpU[0],  d0.x, a0); a1 = dot2bf(wtpU[1],  d0.y, a1);
      a0 = dot2bf(wtpU[2],  d0.z, a0); a1 = dot2bf(wtpU[3],  d0.w, a1);
      a0 = dot2bf(wtpU[4],  d1.x, a0); a1 = dot2bf(wtpU[5],  d1.y, a1);
      a0 = dot2bf(wtpU[6],  d1.z, a0); a1 = dot2bf(wtpU[7],  d1.w, a1);
      a0 = dot2bf(wtpU[8],  c0.x, a0); a1 = dot2bf(wtpU[9],  c0.y, a1);
      a0 = dot2bf(wtpU[10], c0.z, a0); a1 = dot2bf(wtpU[11], c0.w, a1);
      a0 = dot2bf(wtpU[12], c1.x, a0); a1 = dot2bf(wtpU[13], c1.y, a1);
      a0 = dot2bf(wtpU[14], c1.z, a0); a1 = dot2bf(wtpU[15], c1.w, a1);
      spart[tid] = a0 + a1;
    }
    __syncthreads();
    // S1: reduce u over 8 octs
    if (tid < 128) {
      float u = spart[tid];
      #pragma unroll
      for (int o = 1; o < 8; ++o) u += spart[o * 128 + tid];
      su[tid] = u;
    }
    __syncthreads();
    // S2: scores: score[t] = sum_h w2[h]*tanh(E1[t,h]+u[h]) + b2
    {
      float ul = su[lane], uh = su[lane + 64];
      for (int t = wv; t < T_; t += 16) {
        float v = w2a * tanh_(bf2f(sxh[t * 128 + lane]) + ul)
                + w2b * tanh_(bf2f(sxh[t * 128 + 64 + lane]) + uh);
        v = wsum(v);
        if (lane == 0) sscore[t] = v + b2v;
      }
    }
    __syncthreads();
    // S3: softmax over t (wave 0)
    if (wv == 0) {
      float s0 = sscore[lane];
      float s1 = (lane < 36) ? sscore[lane + 64] : -3.0e38f;
      float m  = wmax(fmaxf(s0, s1));
      float e0 = __expf(s0 - m);
      float e1 = (lane < 36) ? __expf(s1 - m) : 0.f;
      float s  = wsum(e0 + e1);
      float iv = rcpf_(s);
      sscore[lane] = e0 * iv;
      if (lane < 36) sscore[lane + 64] = e1 * iv;
    }
    __syncthreads();
    // S4: ctx partials: ctx[h] = sum_t beta[t]*Xe[t,h], t = oct+8i
    {
      float pc = 0.f;
      #pragma unroll
      for (int i = 0; i < 13; ++i) {
        int t = oct + 8 * i;
        if (t < T_) pc += sscore[t] * bf2f(sxe[t * 128 + hh]);
      }
      spart[tid] = pc;
    }
    __syncthreads();
    // S5: ctx final + y_tilde partial
    {
      float v = 0.f;
      if (tid < 128) {
        float cx = spart[tid];
        #pragma unroll
        for (int o = 1; o < 8; ++o) cx += spart[o * 128 + tid];
        sctx[tid] = cx;
        v = fcwv * cx;
      }
      v = wsum(v);
      if (lane == 0 && wv < 2) sred[wv] = v;
    }
    __syncthreads();
    // S6: gates: g[j] = biasD + Wih[j]*y + sum_k Whh[j,k]*d[k]
    {
      float yt = sred[0] + sred[1] + fcbv;
      const uint4* hr4 = (const uint4*)((const u32*)shp + hf * 32);
      float a0 = biasD + wihj * yt, a1 = 0.f;
      #pragma unroll
      for (int i = 0; i < 8; ++i) {
        uint4 hv = hr4[i];
        a0 = dot2bf(wpkD[4*i+0], hv.x, a0);
        a1 = dot2bf(wpkD[4*i+1], hv.y, a1);
        a0 = dot2bf(wpkD[4*i+2], hv.z, a0);
        a1 = dot2bf(wpkD[4*i+3], hv.w, a1);
      }
      float g = a0 + a1;
      g += __shfl_xor(g, 1, 64);
      if (hf == 0) sg[r] = g;
    }
    __syncthreads();
    // S7: pointwise LSTM
    if (tid < 128) {
      float gi = sigm(sg[tid]);
      float gf = sigm(sg[tid + 128]);
      float gg = tanh_(sg[tid + 256]);
      float go = sigm(sg[tid + 384]);
      float c  = gf * sc[tid] + gi * gg;
      sc[tid]  = c;
      float d  = go * tanh_(c);
      sh[tid]  = d;
      shp[tid] = f2bf(d);
      scp[tid] = f2bf(c);
    }
    __syncthreads();
  }

  // ================= head: out = [d, ctx] @ fcfW^T + fcfb =================
  if (tid < C_) {
    float acc = fcfb[tid];
    const float* w = fcfW + (size_t)tid * 256;
    #pragma unroll 8
    for (int k = 0; k < 128; ++k)
      acc += w[k] * sh[k] + w[128 + k] * sctx[k];
    out[(size_t)b * C_ + tid] = acc;
  }
}

extern "C" void kernel_launch(void* const* d_in, const int* in_sizes, int n_in,
                              void* d_out, int out_size, void* d_ws, size_t ws_size,
                              hipStream_t stream) {
  (void)n_in; (void)out_size; (void)d_ws; (void)ws_size;
  const float* X    = (const float*)d_in[0];
  const float* eWih = (const float*)d_in[1];
  const float* eWhh = (const float*)d_in[2];
  const float* ebih = (const float*)d_in[3];
  const float* ebhh = (const float*)d_in[4];
  const float* eAw  = (const float*)d_in[5];
  const float* eAb  = (const float*)d_in[6];
  const float* dW1  = (const float*)d_in[7];
  const float* db1  = (const float*)d_in[8];
  const float* dW2  = (const float*)d_in[9];
  const float* db2  = (const float*)d_in[10];
  const float* dWih = (const float*)d_in[11];
  const float* dWhh = (const float*)d_in[12];
  const float* dbih = (const float*)d_in[13];
  const float* dbhh = (const float*)d_in[14];
  const float* fcW  = (const float*)d_in[15];
  const float* fcb  = (const float*)d_in[16];
  const float* fcfW = (const float*)d_in[17];
  const float* fcfb = (const float*)d_in[18];
  float* out = (float*)d_out;

  const int B = in_sizes[0] / (T_ * 128);
  darnn_fused<<<dim3(B), dim3(NT), 0, stream>>>(
      X, eWih, eWhh, ebih, ebhh, eAw, eAb,
      dW1, db1, dW2, db2, dWih, dWhh, dbih, dbhh,
      fcW, fcb, fcfW, fcfb, out);
}